// Round 13
// baseline (272.905 us; speedup 1.0000x reference)
//
#include <hip/hip_runtime.h>

#define DIMM 2048
#define SEQ 2048
#define NHEAD 32
#define NKV 8
#define QKV_N 3072   // (32 + 2*8) * 64
#define NQ 4096      // BATCH * SEQ
#define VCOL0 2560   // (NHEAD + NKV) * 64 — first V column; = 20 * 128 (tile-aligned)

typedef short bfrag __attribute__((ext_vector_type(8)));   // 8 bf16 = 4 VGPR (MFMA A/B)
typedef short h4 __attribute__((ext_vector_type(4)));      // 4 bf16 = 8B
typedef float ffrag __attribute__((ext_vector_type(4)));   // 4 f32 accumulator
typedef unsigned short u16;

__device__ inline u16 f2bf(float f) {
    union { float f; unsigned int u; } v; v.f = f;
    unsigned int r = (v.u + 0x7FFFu + ((v.u >> 16) & 1u)) >> 16;
    return (u16)r;
}
// pack two non-negative floats to bf16 pair (round-half-up; p>=0 here).
// v_perm_b32 form — BIT-IDENTICAL to the proven shift/and/or form (v5), 3 ops vs 5.
// (v_cvt_pk_bf16_f32 remains banned: round-0 failure, absmax 0.176.)
__device__ inline unsigned int pack2(float a, float b) {
    union { float f; unsigned int u; } x, y; x.f = a; y.f = b;
#if __has_builtin(__builtin_amdgcn_perm)
    return __builtin_amdgcn_perm(y.u + 0x8000u, x.u + 0x8000u, 0x07060302u);
#else
    return ((x.u + 0x8000u) >> 16) | ((y.u + 0x8000u) & 0xFFFF0000u);
#endif
}

// 2^x via the compiler intrinsic (single v_exp_f32 WITH correct hazard handling).
// LESSON (round 5): raw asm("v_exp_f32") NaN'd — VALU-TRANS-use hazard; the
// compiler's hazard recognizer can't see inside inline-asm. Never hand-roll TRANS.
__device__ inline float fexp2(float x) {
#if __has_builtin(__builtin_amdgcn_exp2f)
    return __builtin_amdgcn_exp2f(x);
#else
    return exp2f(x);
#endif
}

__device__ inline void cvt4(const float* __restrict__ src, u16* __restrict__ dst, int i) {
    float4 v = *(const float4*)(src + i);
    h4 o;
    o[0] = (short)f2bf(v.x); o[1] = (short)f2bf(v.y);
    o[2] = (short)f2bf(v.z); o[3] = (short)f2bf(v.w);
    *(h4*)(dst + i) = o;
}

// ---------------- fused fp32->bf16 convert ----------------
// Blocks [0,8192): x. [8192,14336): Wqkv. [14336,18432): Wout (mode 2 only).
// All segment boundaries are block-aligned — no intra-block divergence.
__global__ void cvt_all(const float* __restrict__ x, u16* __restrict__ xb,
                        const float* __restrict__ w, u16* __restrict__ wb,
                        const float* __restrict__ wo, u16* __restrict__ wob) {
    int t = blockIdx.x * blockDim.x + threadIdx.x;
    if (t < 2097152)      cvt4(x, xb, t * 4);
    else if (t < 3670016) cvt4(w, wb, (t - 2097152) * 4);
    else                  cvt4(wo, wob, (t - 3670016) * 4);
}

// async global->LDS, 16B per lane; LDS dest is wave-uniform base + lane*16 (HW rule)
__device__ inline void gl_lds16(const u16* g, u16* l) {
    __builtin_amdgcn_global_load_lds(
        (const __attribute__((address_space(1))) unsigned int*)g,
        (__attribute__((address_space(3))) unsigned int*)l, 16, 0, 0);
}

// Stage R x 64 bf16 tile (row stride gstride elems) into LDS via global_load_lds.
// XOR swizzle: LDS chunk p of row r holds global chunk p^(r&7). Conflict-free.
template<int R>
__device__ inline void stage64(const u16* __restrict__ g, int gstride, u16* lds) {
    int tid = threadIdx.x, w = tid >> 6, l = tid & 63;
#pragma unroll
    for (int i = 0; i < R / 32; ++i) {
        int row = w * (R / 4) + i * 8 + (l >> 3);
        int c = (l & 7) ^ (row & 7);
        gl_lds16(g + (size_t)row * gstride + c * 8, lds + (w * (R / 4) + i * 8) * 64);
    }
}

__device__ inline bfrag frag64(const u16* lds, int row, int ch) {
    return *(const bfrag*)(lds + row * 64 + (ch ^ (row & 7)) * 8);
}

// ---------------- NT GEMM (m97 single-buffer) ----------------
// C[M][N] = A[M][K] @ B[N][K]^T, bf16 in, fp32 accum. 128x128 tile, BK=64.
// LDS 36 KB; 3 blocks/CU. Measured: ~873-934 TF — AT the m97-structure ceiling.
// 256²/8-phase rejected (tile under-fill at these shapes + unreconstructable
// counted-vmcnt schedule). NO setprio here (m190: null/negative on lockstep GEMM).
// SCALEQ: Q columns scaled by 1/sqrt(64)*log2(e) for attn's exp2.
// vt != nullptr (GEMM1, fusion modes): V columns (n0 >= VCOL0, block-uniform)
// written TRANSPOSED directly to vt (bit-identical to post_gemm1's transpose).
template<bool CF32, bool SCALEQ>
__global__ __launch_bounds__(256, 3) void gemm_nt(const u16* __restrict__ A,
                                                  const u16* __restrict__ B,
                                                  void* __restrict__ Cp, int M, int N, int K,
                                                  u16* __restrict__ vt) {
    __shared__ u16 As[128 * 64];
    __shared__ u16 Bs[128 * 64];
    int tid = threadIdx.x, lane = tid & 63, w = tid >> 6;
    int quad = lane >> 4, n16 = lane & 15;
    int wm = w >> 1, wn = w & 1;
    int m0 = blockIdx.y * 128, n0 = blockIdx.x * 128;

    ffrag acc[4][4] = {};
    for (int k0 = 0; k0 < K; k0 += 64) {
        stage64<128>(A + (size_t)m0 * K + k0, K, As);
        stage64<128>(B + (size_t)n0 * K + k0, K, Bs);
        __syncthreads();
#pragma unroll
        for (int ks = 0; ks < 2; ++ks) {
            bfrag a[4], b[4];
#pragma unroll
            for (int t = 0; t < 4; ++t) a[t] = frag64(As, wm * 64 + t * 16 + n16, ks * 4 + quad);
#pragma unroll
            for (int t = 0; t < 4; ++t) b[t] = frag64(Bs, wn * 64 + t * 16 + n16, ks * 4 + quad);
#pragma unroll
            for (int ti = 0; ti < 4; ++ti)
#pragma unroll
                for (int tj = 0; tj < 4; ++tj)
                    acc[ti][tj] = __builtin_amdgcn_mfma_f32_16x16x32_bf16(a[ti], b[tj], acc[ti][tj], 0, 0, 0);
        }
        __syncthreads();
    }
    // C/D layout: col = lane&15, row = quad*4 + r
    if (SCALEQ && vt != nullptr && n0 >= VCOL0) {
        // V-fusion epilogue (block-uniform branch): write vt[(b*8+kh)*64+d][s]
#pragma unroll
        for (int ti = 0; ti < 4; ++ti) {
            int row0 = m0 + wm * 64 + ti * 16 + quad * 4;  // 4 consecutive rows = s0..s0+3
            int bb = row0 >> 11, s0 = row0 & (SEQ - 1);
#pragma unroll
            for (int tj = 0; tj < 4; ++tj) {
                int col = n0 + wn * 64 + tj * 16 + n16;
                int kh = (col - VCOL0) >> 6, d = col & 63;
                uint2 pk;
                pk.x = (unsigned)f2bf(acc[ti][tj][0]) | ((unsigned)f2bf(acc[ti][tj][1]) << 16);
                pk.y = (unsigned)f2bf(acc[ti][tj][2]) | ((unsigned)f2bf(acc[ti][tj][3]) << 16);
                *(uint2*)(vt + (size_t)((bb * 8 + kh) * 64 + d) * SEQ + s0) = pk;
            }
        }
        return;
    }
#pragma unroll
    for (int ti = 0; ti < 4; ++ti) {
        int row = m0 + wm * 64 + ti * 16 + quad * 4;
#pragma unroll
        for (int tj = 0; tj < 4; ++tj) {
            int col = n0 + wn * 64 + tj * 16 + n16;
            // 0.125 * log2(e) = 0.18033688011112042
            float sc = (SCALEQ && col < NHEAD * 64) ? 0.18033688011112042f : 1.0f;
#pragma unroll
            for (int r = 0; r < 4; ++r) {
                if (CF32) ((float*)Cp)[(size_t)(row + r) * N + col] = acc[ti][tj][r];
                else      ((u16*)Cp)[(size_t)(row + r) * N + col] = f2bf(acc[ti][tj][r] * sc);
            }
        }
    }
}

// ---------------- post-GEMM1 pass (fallback modes only) ----------------
__global__ void post_gemm1(const u16* __restrict__ qkv, u16* __restrict__ vt,
                           const float* __restrict__ Wout, u16* __restrict__ Woutb) {
    __shared__ u16 t[64][72];
    int bid = blockIdx.x, tid = threadIdx.x;
    if (bid < 4096) {
        cvt4(Wout, Woutb, (bid * 256 + tid) * 4);
        return;
    }
    int idx = bid - 4096;
    int s0 = (idx & 31) * 64, kh = (idx >> 5) & 7, b = idx >> 8;
    {
        int r = tid >> 2, c = tid & 3;
        const u16* gp = qkv + (size_t)(b * SEQ + s0 + r) * QKV_N + (NHEAD + NKV + kh) * 64 + c * 16;
        *(bfrag*)&t[r][c * 16] = *(const bfrag*)gp;
        *(bfrag*)&t[r][c * 16 + 8] = *(const bfrag*)(gp + 8);
    }
    __syncthreads();
    {
        int d = tid >> 2, c = tid & 3;
        u16* op = vt + (size_t)((b * 8 + kh) * 64 + d) * SEQ + s0 + c * 16;
        bfrag v0, v1;
#pragma unroll
        for (int j = 0; j < 8; ++j) ((u16*)&v0)[j] = t[c * 16 + j][d];
#pragma unroll
        for (int j = 0; j < 8; ++j) ((u16*)&v1)[j] = t[c * 16 + 8 + j][d];
        *(bfrag*)op = v0;
        *(bfrag*)(op + 8) = v1;
    }
}

// ---------------- Flash attention v14 (REVERTED from v16; round-11 best state) ----------------
// v16's GQA K/V-sharing 8-wave blocks REJECTED (round 12): FETCH did NOT halve
// (12.35 MB unchanged — L2 was already absorbing cross-head K/V duplicates via
// the heavy-first dispatch), so the fusion saved only LDS-write instructions
// (conflicts 3.34M->2.23M) while paying coarser 512-thread barriers
// (MfmaUtil 29.9->27.1) -> attn 55->59.5 µs. Traffic optimizations must target
// a bottlenecked tier; K/V was L2-resident.
// v14: Ps XOR-swizzled [128][64], P-reads conflict-free via frag64 (GEMM-proven);
// setprio kept (round 9: −1.5-2 µs, m191 regime). v12's bpermute REJECTED.
// v9 invariants (PROTECT): linear heavy-first dispatch qb = 15-(id>>6) — fixes
// drain tail AND gives L2 K/V sharing (FETCH 43->12 MB); ones-column MFMA
// denominator in C-layout; exp2 with log2e folded into Q scale at GEMM1.
// LDS: 16K (K) + 16K (V) + 16K (Ps) = 48 KB -> 3 blocks/CU.

template<bool MASKED>
__device__ inline void st_phase(int kb, int rowbase, int quad, int n16, int wrow,
                                const bfrag qf[2][2], const u16* Ks, u16* Ps) {
#pragma unroll
    for (int tj = 0; tj < 4; ++tj) {
        bfrag kf0 = frag64(Ks, tj * 16 + n16, quad);
        bfrag kf1 = frag64(Ks, tj * 16 + n16, 4 + quad);
        ffrag st[2] = {};
        __builtin_amdgcn_s_setprio(1);
#pragma unroll
        for (int ti = 0; ti < 2; ++ti) {
            st[ti] = __builtin_amdgcn_mfma_f32_16x16x32_bf16(kf0, qf[ti][0], st[ti], 0, 0, 0);
            st[ti] = __builtin_amdgcn_mfma_f32_16x16x32_bf16(kf1, qf[ti][1], st[ti], 0, 0, 0);
        }
        __builtin_amdgcn_s_setprio(0);
        int key0 = kb * 64 + tj * 16 + quad * 4;  // this lane's 4 consecutive keys
#pragma unroll
        for (int ti = 0; ti < 2; ++ti) {
            int qrow = rowbase + ti * 16 + n16;   // global q row (col of S^T tile)
            float p[4];
#pragma unroll
            for (int r = 0; r < 4; ++r) {
                float e = fexp2(st[ti][r]);
                if (MASKED && (key0 + r > qrow)) e = 0.f;
                p[r] = e;
            }
            uint2 pk; pk.x = pack2(p[0], p[1]); pk.y = pack2(p[2], p[3]);
            // swizzled write: logical col tj*16+quad*4 -> chunk tj*2+(quad>>1),
            // chunk stored at ^(row&7), half-offset (quad&1)*4. 8B-aligned.
            int prow = wrow + ti * 16 + n16;
            int c0 = (tj * 2 + (quad >> 1)) ^ (prow & 7);
            *(uint2*)(Ps + prow * 64 + c0 * 8 + (quad & 1) * 4) = pk;
        }
    }
}

__device__ inline void pv_phase(const bfrag pf[4], const u16* Vs, ffrag o[2][4],
                                ffrag ol[2], bfrag ones, int quad, int n16) {
#pragma unroll
    for (int ks = 0; ks < 2; ++ks) {
        bfrag vf[4];
#pragma unroll
        for (int dj = 0; dj < 4; ++dj) vf[dj] = frag64(Vs, dj * 16 + n16, ks * 4 + quad);
        __builtin_amdgcn_s_setprio(1);
#pragma unroll
        for (int ti = 0; ti < 2; ++ti) {
#pragma unroll
            for (int dj = 0; dj < 4; ++dj)
                o[ti][dj] = __builtin_amdgcn_mfma_f32_16x16x32_bf16(pf[ks * 2 + ti], vf[dj], o[ti][dj], 0, 0, 0);
            // denominator: l = P @ 1 — already in C-layout (row = quad*4 + r)
            ol[ti] = __builtin_amdgcn_mfma_f32_16x16x32_bf16(pf[ks * 2 + ti], ones, ol[ti], 0, 0, 0);
        }
        __builtin_amdgcn_s_setprio(0);
    }
}

__global__ __launch_bounds__(256, 3) void attn(const u16* __restrict__ qkv,
                                               const u16* __restrict__ vt,
                                               u16* __restrict__ aout) {
    __shared__ u16 Ks[2][64 * 64];
    __shared__ u16 Vs[2][64 * 64];
    __shared__ u16 Ps[128 * 64];

    int tid = threadIdx.x, lane = tid & 63, w = tid >> 6;
    int quad = lane >> 4, n16 = lane & 15;
    // linear heavy-first mapping: blocks 0..63 are qb=15 (heaviest), last 64 are qb=0
    int id = blockIdx.x;
    int qb = 15 - (id >> 6);
    int h = id & 31, b = (id >> 5) & 1;
    int kh = h & 7;  // jnp.tile semantics: kv head = h % NKV
    int wrow = w * 32;  // wave's local row base in Ps

    bfrag ones;
#pragma unroll
    for (int j = 0; j < 8; ++j) ((u16*)&ones)[j] = (short)0x3F80;  // bf16 1.0

    const u16* Qg = qkv + (size_t)(b * SEQ) * QKV_N + h * 64;  // pre-scaled by log2e/8
    const u16* Kg = qkv + (size_t)(b * SEQ) * QKV_N + (NHEAD + kh) * 64;
    const u16* Vg = vt + (size_t)((b * 8 + kh) * 64) * SEQ;

    int q0 = qb * 128;
    int rowbase = q0 + wrow;

    // Q fragments straight from global (B-operand layout: n16 = q-row, quad = d-chunk)
    bfrag qf[2][2];
#pragma unroll
    for (int ti = 0; ti < 2; ++ti)
#pragma unroll
        for (int ks = 0; ks < 2; ++ks)
            qf[ti][ks] = *(const bfrag*)(Qg + (size_t)(rowbase + ti * 16 + n16) * QKV_N + ks * 32 + quad * 8);

    ffrag o[2][4] = {};
    ffrag ol[2] = {};
    bfrag pf[4];

    int nkb = 2 * qb + 2;  // 64-key blocks covering keys <= q0+127
    stage64<64>(Kg, QKV_N, Ks[0]);
    __syncthreads();
    for (int i = 0; i <= nkb; ++i) {
        // prefetch: K one block ahead, V for the current S^T block (lag-1 consumer)
        if (i + 1 < nkb) stage64<64>(Kg + (size_t)((i + 1) * 64) * QKV_N, QKV_N, Ks[(i + 1) & 1]);
        if (i < nkb)     stage64<64>(Vg + i * 64, SEQ, Vs[i & 1]);
        if (i > 0) {
            // read P(i-1) into regs — written last iteration, no lgkm stall.
            // frag64 = swizzle-matched read, conflict-free (GEMM-proven pattern).
#pragma unroll
            for (int ks = 0; ks < 2; ++ks)
#pragma unroll
                for (int ti = 0; ti < 2; ++ti)
                    pf[ks * 2 + ti] = frag64(Ps, wrow + ti * 16 + n16, ks * 4 + quad);
        }
        if (i < nkb) {
            if (i >= nkb - 2) st_phase<true>(i, rowbase, quad, n16, wrow, qf, Ks[i & 1], Ps);
            else              st_phase<false>(i, rowbase, quad, n16, wrow, qf, Ks[i & 1], Ps);
        }
        if (i > 0) pv_phase(pf, Vs[(i - 1) & 1], o, ol, ones, quad, n16);
        __syncthreads();  // drains prefetch (after compute) + guards buffer reuse
    }

    // ol[ti][r] holds the row-sum for qrow = rowbase + ti*16 + quad*4 + r
    // (identical across n16) — already in C-layout, no cross-lane reduce needed.
#pragma unroll
    for (int ti = 0; ti < 2; ++ti) {
#pragma unroll
        for (int r = 0; r < 4; ++r) {
            float inv = 1.f / ol[ti][r];
            size_t rg = (size_t)(b * SEQ + rowbase + ti * 16 + quad * 4 + r) * DIMM + h * 64;
#pragma unroll
            for (int dj = 0; dj < 4; ++dj)
                aout[rg + dj * 16 + n16] = f2bf(o[ti][dj][r] * inv);
        }
    }
}

extern "C" void kernel_launch(void* const* d_in, const int* in_sizes, int n_in,
                              void* d_out, int out_size, void* d_ws, size_t ws_size,
                              hipStream_t stream) {
    const float* x    = (const float*)d_in[0];  // [4096][2048] fp32
    const float* Wqkv = (const float*)d_in[1];  // [3072][2048] fp32
    const float* Wout = (const float*)d_in[2];  // [2048][2048] fp32
    // d_in[3] = mask (fp32): causal applied analytically in-kernel
    float* out = (float*)d_out;                 // [4096][2048] fp32

    // Workspace, aliased by sequential lifetime (all offsets in u16 elems):
    //   qkv      [0, 24 MiB)   — live GEMM1 .. attn (V cols unwritten in modes 1/2)
    //   xb/aout  [24, 40 MiB)  — xb: cvt..GEMM1; aout: attn..GEMM2
    //   Wqkvb    [40, 52 MiB)  — cvt..GEMM1
    // mode 0 (ws < 56 MiB):  vtb aliases Wqkvb@40, Woutb@44 — both post-GEMM1
    // mode 1 (ws >= 56 MiB): vtb@52 (written by GEMM1 epilogue), Woutb@44 post-GEMM1
    // mode 2 (ws >= 64 MiB): vtb@52, Woutb@56 (cvt'd up front) — post_gemm1 ELIMINATED
    u16* qkv   = (u16*)d_ws;
    u16* xb    = qkv + (size_t)NQ * QKV_N;       // elem 12,582,912
    u16* aout  = xb;
    u16* R     = xb + (size_t)NQ * DIMM;         // elem 20,971,520 (40 MiB)
    const size_t MiB = 1024 * 1024;
    int mode = (ws_size >= 64 * MiB) ? 2 : (ws_size >= 56 * MiB) ? 1 : 0;
    u16* Wqkvb = R;                                           // 12 MiB
    u16* vtb   = (mode >= 1) ? R + 6291456 : R;               // fused: @52 MiB; else old
    u16* Woutb = (mode == 2) ? R + 6291456 + 2097152          // @56 MiB
                             : R + 2097152;                   // @44 MiB (post-GEMM1)
    u16* g1vt  = (mode >= 1) ? vtb : nullptr;                 // enables V-fusion epilogue

    dim3 blk(256);
    // mode 2: convert x + Wqkv + Wout up front (18432 blocks); else x + Wqkv (14336)
    cvt_all<<<(mode == 2 ? 18432 : 14336), blk, 0, stream>>>(x, xb, Wqkv, Wqkvb, Wout, Woutb);
    gemm_nt<false, true><<<dim3(QKV_N / 128, NQ / 128), blk, 0, stream>>>(xb, Wqkvb, qkv, NQ, QKV_N, DIMM, g1vt);
    if (mode == 0)      post_gemm1<<<4608, blk, 0, stream>>>(qkv, vtb, Wout, Woutb);
    else if (mode == 1) post_gemm1<<<4096, blk, 0, stream>>>(qkv, vtb, Wout, Woutb);
    // mode 2: no post_gemm1 — V written by GEMM1, Wout converted by cvt_all
    attn<<<dim3(1024), blk, 0, stream>>>(qkv, vtb, aout);
    gemm_nt<true, false><<<dim3(DIMM / 128, NQ / 128), blk, 0, stream>>>(aout, Woutb, out, NQ, DIMM, DIMM, nullptr);
}

// Round 14
// 271.683 us; speedup vs baseline: 1.0045x; 1.0045x over previous
//
#include <hip/hip_runtime.h>

#define DIMM 2048
#define SEQ 2048
#define NHEAD 32
#define NKV 8
#define QKV_N 3072   // (32 + 2*8) * 64
#define NQ 4096      // BATCH * SEQ
#define VCOL0 2560   // (NHEAD + NKV) * 64 — first V column; = 20 * 128 (tile-aligned)

typedef short bfrag __attribute__((ext_vector_type(8)));   // 8 bf16 = 4 VGPR (MFMA A/B)
typedef short h4 __attribute__((ext_vector_type(4)));      // 4 bf16 = 8B
typedef float ffrag __attribute__((ext_vector_type(4)));   // 4 f32 accumulator
typedef unsigned short u16;

__device__ inline u16 f2bf(float f) {
    union { float f; unsigned int u; } v; v.f = f;
    unsigned int r = (v.u + 0x7FFFu + ((v.u >> 16) & 1u)) >> 16;
    return (u16)r;
}
// pack two non-negative floats to bf16 pair (round-half-up; p>=0 here).
// v_perm_b32 form — BIT-IDENTICAL to the proven shift/and/or form (v5), 3 ops vs 5.
// (v_cvt_pk_bf16_f32 remains banned: round-0 failure, absmax 0.176.)
__device__ inline unsigned int pack2(float a, float b) {
    union { float f; unsigned int u; } x, y; x.f = a; y.f = b;
#if __has_builtin(__builtin_amdgcn_perm)
    return __builtin_amdgcn_perm(y.u + 0x8000u, x.u + 0x8000u, 0x07060302u);
#else
    return ((x.u + 0x8000u) >> 16) | ((y.u + 0x8000u) & 0xFFFF0000u);
#endif
}

// 2^x via the compiler intrinsic (single v_exp_f32 WITH correct hazard handling).
// LESSON (round 5): raw asm("v_exp_f32") NaN'd — VALU-TRANS-use hazard; the
// compiler's hazard recognizer can't see inside inline-asm. Never hand-roll TRANS.
__device__ inline float fexp2(float x) {
#if __has_builtin(__builtin_amdgcn_exp2f)
    return __builtin_amdgcn_exp2f(x);
#else
    return exp2f(x);
#endif
}

__device__ inline void cvt4(const float* __restrict__ src, u16* __restrict__ dst, int i) {
    float4 v = *(const float4*)(src + i);
    h4 o;
    o[0] = (short)f2bf(v.x); o[1] = (short)f2bf(v.y);
    o[2] = (short)f2bf(v.z); o[3] = (short)f2bf(v.w);
    *(h4*)(dst + i) = o;
}

// ---------------- fused fp32->bf16 convert ----------------
// Blocks [0,8192): x. [8192,14336): Wqkv. [14336,18432): Wout (mode 2 only).
// All segment boundaries are block-aligned — no intra-block divergence.
__global__ void cvt_all(const float* __restrict__ x, u16* __restrict__ xb,
                        const float* __restrict__ w, u16* __restrict__ wb,
                        const float* __restrict__ wo, u16* __restrict__ wob) {
    int t = blockIdx.x * blockDim.x + threadIdx.x;
    if (t < 2097152)      cvt4(x, xb, t * 4);
    else if (t < 3670016) cvt4(w, wb, (t - 2097152) * 4);
    else                  cvt4(wo, wob, (t - 3670016) * 4);
}

// async global->LDS, 16B per lane; LDS dest is wave-uniform base + lane*16 (HW rule)
__device__ inline void gl_lds16(const u16* g, u16* l) {
    __builtin_amdgcn_global_load_lds(
        (const __attribute__((address_space(1))) unsigned int*)g,
        (__attribute__((address_space(3))) unsigned int*)l, 16, 0, 0);
}

// Stage R x 64 bf16 tile (row stride gstride elems) into LDS via global_load_lds.
// XOR swizzle: LDS chunk p of row r holds global chunk p^(r&7). Conflict-free.
template<int R>
__device__ inline void stage64(const u16* __restrict__ g, int gstride, u16* lds) {
    int tid = threadIdx.x, w = tid >> 6, l = tid & 63;
#pragma unroll
    for (int i = 0; i < R / 32; ++i) {
        int row = w * (R / 4) + i * 8 + (l >> 3);
        int c = (l & 7) ^ (row & 7);
        gl_lds16(g + (size_t)row * gstride + c * 8, lds + (w * (R / 4) + i * 8) * 64);
    }
}

__device__ inline bfrag frag64(const u16* lds, int row, int ch) {
    return *(const bfrag*)(lds + row * 64 + (ch ^ (row & 7)) * 8);
}

// ---------------- NT GEMM (m97 single-buffer, tile-templated) ----------------
// C[M][N] = A[M][K] @ B[N][K]^T, bf16 in, fp32 accum. BMxBN tile, BK=64.
// 2x2 waves, wave tile (BM/2)x(BN/2), acc[BM/32][BN/32].
// GEMM1 (128x128): 768 blocks = 3/CU exact, ~908 TF — AT the m97-structure ceiling.
// GEMM2 (64x128): round-13 found 128² gave 512 blocks = 2/CU -> 607 TF (33% below
// ceiling; this structure's latency hiding IS cross-block overlap, needs >=3/CU).
// 64x128 -> 1024 blocks = 4/CU, LDS 24 KB. Same K-accumulation order per output
// element -> bit-identical fp32 C.
// 256²/8-phase rejected (tile under-fill + unreconstructable schedule).
// NO setprio here (m190: null/negative on lockstep GEMM).
// SCALEQ: Q columns scaled by 1/sqrt(64)*log2(e) for attn's exp2.
// vt != nullptr (GEMM1, fusion modes): V columns (n0 >= VCOL0, block-uniform)
// written TRANSPOSED directly to vt (bit-identical to post_gemm1's transpose).
template<bool CF32, bool SCALEQ, int BM, int BN>
__global__ __launch_bounds__(256, (BM * BN == 16384) ? 3 : 4)
void gemm_nt(const u16* __restrict__ A, const u16* __restrict__ B,
             void* __restrict__ Cp, int M, int N, int K, u16* __restrict__ vt) {
    constexpr int TI = BM / 32;  // 16-row tiles per wave
    constexpr int TJ = BN / 32;  // 16-col tiles per wave
    __shared__ u16 As[BM * 64];
    __shared__ u16 Bs[BN * 64];
    int tid = threadIdx.x, lane = tid & 63, w = tid >> 6;
    int quad = lane >> 4, n16 = lane & 15;
    int wm = w >> 1, wn = w & 1;
    int m0 = blockIdx.y * BM, n0 = blockIdx.x * BN;

    ffrag acc[TI][TJ] = {};
    for (int k0 = 0; k0 < K; k0 += 64) {
        stage64<BM>(A + (size_t)m0 * K + k0, K, As);
        stage64<BN>(B + (size_t)n0 * K + k0, K, Bs);
        __syncthreads();
#pragma unroll
        for (int ks = 0; ks < 2; ++ks) {
            bfrag a[TI], b[TJ];
#pragma unroll
            for (int t = 0; t < TI; ++t) a[t] = frag64(As, wm * (BM / 2) + t * 16 + n16, ks * 4 + quad);
#pragma unroll
            for (int t = 0; t < TJ; ++t) b[t] = frag64(Bs, wn * (BN / 2) + t * 16 + n16, ks * 4 + quad);
#pragma unroll
            for (int ti = 0; ti < TI; ++ti)
#pragma unroll
                for (int tj = 0; tj < TJ; ++tj)
                    acc[ti][tj] = __builtin_amdgcn_mfma_f32_16x16x32_bf16(a[ti], b[tj], acc[ti][tj], 0, 0, 0);
        }
        __syncthreads();
    }
    // C/D layout: col = lane&15, row = quad*4 + r
    if constexpr (SCALEQ) {
        if (vt != nullptr && n0 >= VCOL0) {
            // V-fusion epilogue (block-uniform branch): write vt[(b*8+kh)*64+d][s]
#pragma unroll
            for (int ti = 0; ti < TI; ++ti) {
                int row0 = m0 + wm * (BM / 2) + ti * 16 + quad * 4;  // 4 consecutive rows = s0..s0+3
                int bb = row0 >> 11, s0 = row0 & (SEQ - 1);
#pragma unroll
                for (int tj = 0; tj < TJ; ++tj) {
                    int col = n0 + wn * (BN / 2) + tj * 16 + n16;
                    int kh = (col - VCOL0) >> 6, d = col & 63;
                    uint2 pk;
                    pk.x = (unsigned)f2bf(acc[ti][tj][0]) | ((unsigned)f2bf(acc[ti][tj][1]) << 16);
                    pk.y = (unsigned)f2bf(acc[ti][tj][2]) | ((unsigned)f2bf(acc[ti][tj][3]) << 16);
                    *(uint2*)(vt + (size_t)((bb * 8 + kh) * 64 + d) * SEQ + s0) = pk;
                }
            }
            return;
        }
    }
#pragma unroll
    for (int ti = 0; ti < TI; ++ti) {
        int row = m0 + wm * (BM / 2) + ti * 16 + quad * 4;
#pragma unroll
        for (int tj = 0; tj < TJ; ++tj) {
            int col = n0 + wn * (BN / 2) + tj * 16 + n16;
            // 0.125 * log2(e) = 0.18033688011112042
            float sc = (SCALEQ && col < NHEAD * 64) ? 0.18033688011112042f : 1.0f;
#pragma unroll
            for (int r = 0; r < 4; ++r) {
                if (CF32) ((float*)Cp)[(size_t)(row + r) * N + col] = acc[ti][tj][r];
                else      ((u16*)Cp)[(size_t)(row + r) * N + col] = f2bf(acc[ti][tj][r] * sc);
            }
        }
    }
}

// ---------------- post-GEMM1 pass (fallback modes only) ----------------
__global__ void post_gemm1(const u16* __restrict__ qkv, u16* __restrict__ vt,
                           const float* __restrict__ Wout, u16* __restrict__ Woutb) {
    __shared__ u16 t[64][72];
    int bid = blockIdx.x, tid = threadIdx.x;
    if (bid < 4096) {
        cvt4(Wout, Woutb, (bid * 256 + tid) * 4);
        return;
    }
    int idx = bid - 4096;
    int s0 = (idx & 31) * 64, kh = (idx >> 5) & 7, b = idx >> 8;
    {
        int r = tid >> 2, c = tid & 3;
        const u16* gp = qkv + (size_t)(b * SEQ + s0 + r) * QKV_N + (NHEAD + NKV + kh) * 64 + c * 16;
        *(bfrag*)&t[r][c * 16] = *(const bfrag*)gp;
        *(bfrag*)&t[r][c * 16 + 8] = *(const bfrag*)(gp + 8);
    }
    __syncthreads();
    {
        int d = tid >> 2, c = tid & 3;
        u16* op = vt + (size_t)((b * 8 + kh) * 64 + d) * SEQ + s0 + c * 16;
        bfrag v0, v1;
#pragma unroll
        for (int j = 0; j < 8; ++j) ((u16*)&v0)[j] = t[c * 16 + j][d];
#pragma unroll
        for (int j = 0; j < 8; ++j) ((u16*)&v1)[j] = t[c * 16 + 8 + j][d];
        *(bfrag*)op = v0;
        *(bfrag*)(op + 8) = v1;
    }
}

// ---------------- Flash attention v14 (round-11 best state) ----------------
// v16's GQA K/V-sharing 8-wave blocks REJECTED (round 12): FETCH did NOT halve
// (L2 already absorbed cross-head K/V duplicates via heavy-first dispatch);
// coarser 512-thread barriers cost MfmaUtil 29.9->27.1 -> 55->59.5 µs.
// v14: Ps XOR-swizzled [128][64], P-reads conflict-free via frag64 (GEMM-proven);
// setprio kept (round 9: −1.5-2 µs, m191 regime). v12's bpermute REJECTED.
// v9 invariants (PROTECT): linear heavy-first dispatch qb = 15-(id>>6) — fixes
// drain tail AND gives L2 K/V sharing (FETCH 43->12 MB); ones-column MFMA
// denominator in C-layout; exp2 with log2e folded into Q scale at GEMM1.
// LDS: 16K (K) + 16K (V) + 16K (Ps) = 48 KB -> 3 blocks/CU.

template<bool MASKED>
__device__ inline void st_phase(int kb, int rowbase, int quad, int n16, int wrow,
                                const bfrag qf[2][2], const u16* Ks, u16* Ps) {
#pragma unroll
    for (int tj = 0; tj < 4; ++tj) {
        bfrag kf0 = frag64(Ks, tj * 16 + n16, quad);
        bfrag kf1 = frag64(Ks, tj * 16 + n16, 4 + quad);
        ffrag st[2] = {};
        __builtin_amdgcn_s_setprio(1);
#pragma unroll
        for (int ti = 0; ti < 2; ++ti) {
            st[ti] = __builtin_amdgcn_mfma_f32_16x16x32_bf16(kf0, qf[ti][0], st[ti], 0, 0, 0);
            st[ti] = __builtin_amdgcn_mfma_f32_16x16x32_bf16(kf1, qf[ti][1], st[ti], 0, 0, 0);
        }
        __builtin_amdgcn_s_setprio(0);
        int key0 = kb * 64 + tj * 16 + quad * 4;  // this lane's 4 consecutive keys
#pragma unroll
        for (int ti = 0; ti < 2; ++ti) {
            int qrow = rowbase + ti * 16 + n16;   // global q row (col of S^T tile)
            float p[4];
#pragma unroll
            for (int r = 0; r < 4; ++r) {
                float e = fexp2(st[ti][r]);
                if (MASKED && (key0 + r > qrow)) e = 0.f;
                p[r] = e;
            }
            uint2 pk; pk.x = pack2(p[0], p[1]); pk.y = pack2(p[2], p[3]);
            // swizzled write: logical col tj*16+quad*4 -> chunk tj*2+(quad>>1),
            // chunk stored at ^(row&7), half-offset (quad&1)*4. 8B-aligned.
            int prow = wrow + ti * 16 + n16;
            int c0 = (tj * 2 + (quad >> 1)) ^ (prow & 7);
            *(uint2*)(Ps + prow * 64 + c0 * 8 + (quad & 1) * 4) = pk;
        }
    }
}

__device__ inline void pv_phase(const bfrag pf[4], const u16* Vs, ffrag o[2][4],
                                ffrag ol[2], bfrag ones, int quad, int n16) {
#pragma unroll
    for (int ks = 0; ks < 2; ++ks) {
        bfrag vf[4];
#pragma unroll
        for (int dj = 0; dj < 4; ++dj) vf[dj] = frag64(Vs, dj * 16 + n16, ks * 4 + quad);
        __builtin_amdgcn_s_setprio(1);
#pragma unroll
        for (int ti = 0; ti < 2; ++ti) {
#pragma unroll
            for (int dj = 0; dj < 4; ++dj)
                o[ti][dj] = __builtin_amdgcn_mfma_f32_16x16x32_bf16(pf[ks * 2 + ti], vf[dj], o[ti][dj], 0, 0, 0);
            // denominator: l = P @ 1 — already in C-layout (row = quad*4 + r)
            ol[ti] = __builtin_amdgcn_mfma_f32_16x16x32_bf16(pf[ks * 2 + ti], ones, ol[ti], 0, 0, 0);
        }
        __builtin_amdgcn_s_setprio(0);
    }
}

__global__ __launch_bounds__(256, 3) void attn(const u16* __restrict__ qkv,
                                               const u16* __restrict__ vt,
                                               u16* __restrict__ aout) {
    __shared__ u16 Ks[2][64 * 64];
    __shared__ u16 Vs[2][64 * 64];
    __shared__ u16 Ps[128 * 64];

    int tid = threadIdx.x, lane = tid & 63, w = tid >> 6;
    int quad = lane >> 4, n16 = lane & 15;
    // linear heavy-first mapping: blocks 0..63 are qb=15 (heaviest), last 64 are qb=0
    int id = blockIdx.x;
    int qb = 15 - (id >> 6);
    int h = id & 31, b = (id >> 5) & 1;
    int kh = h & 7;  // jnp.tile semantics: kv head = h % NKV
    int wrow = w * 32;  // wave's local row base in Ps

    bfrag ones;
#pragma unroll
    for (int j = 0; j < 8; ++j) ((u16*)&ones)[j] = (short)0x3F80;  // bf16 1.0

    const u16* Qg = qkv + (size_t)(b * SEQ) * QKV_N + h * 64;  // pre-scaled by log2e/8
    const u16* Kg = qkv + (size_t)(b * SEQ) * QKV_N + (NHEAD + kh) * 64;
    const u16* Vg = vt + (size_t)((b * 8 + kh) * 64) * SEQ;

    int q0 = qb * 128;
    int rowbase = q0 + wrow;

    // Q fragments straight from global (B-operand layout: n16 = q-row, quad = d-chunk)
    bfrag qf[2][2];
#pragma unroll
    for (int ti = 0; ti < 2; ++ti)
#pragma unroll
        for (int ks = 0; ks < 2; ++ks)
            qf[ti][ks] = *(const bfrag*)(Qg + (size_t)(rowbase + ti * 16 + n16) * QKV_N + ks * 32 + quad * 8);

    ffrag o[2][4] = {};
    ffrag ol[2] = {};
    bfrag pf[4];

    int nkb = 2 * qb + 2;  // 64-key blocks covering keys <= q0+127
    stage64<64>(Kg, QKV_N, Ks[0]);
    __syncthreads();
    for (int i = 0; i <= nkb; ++i) {
        // prefetch: K one block ahead, V for the current S^T block (lag-1 consumer)
        if (i + 1 < nkb) stage64<64>(Kg + (size_t)((i + 1) * 64) * QKV_N, QKV_N, Ks[(i + 1) & 1]);
        if (i < nkb)     stage64<64>(Vg + i * 64, SEQ, Vs[i & 1]);
        if (i > 0) {
            // read P(i-1) into regs — written last iteration, no lgkm stall.
            // frag64 = swizzle-matched read, conflict-free (GEMM-proven pattern).
#pragma unroll
            for (int ks = 0; ks < 2; ++ks)
#pragma unroll
                for (int ti = 0; ti < 2; ++ti)
                    pf[ks * 2 + ti] = frag64(Ps, wrow + ti * 16 + n16, ks * 4 + quad);
        }
        if (i < nkb) {
            if (i >= nkb - 2) st_phase<true>(i, rowbase, quad, n16, wrow, qf, Ks[i & 1], Ps);
            else              st_phase<false>(i, rowbase, quad, n16, wrow, qf, Ks[i & 1], Ps);
        }
        if (i > 0) pv_phase(pf, Vs[(i - 1) & 1], o, ol, ones, quad, n16);
        __syncthreads();  // drains prefetch (after compute) + guards buffer reuse
    }

    // ol[ti][r] holds the row-sum for qrow = rowbase + ti*16 + quad*4 + r
    // (identical across n16) — already in C-layout, no cross-lane reduce needed.
#pragma unroll
    for (int ti = 0; ti < 2; ++ti) {
#pragma unroll
        for (int r = 0; r < 4; ++r) {
            float inv = 1.f / ol[ti][r];
            size_t rg = (size_t)(b * SEQ + rowbase + ti * 16 + quad * 4 + r) * DIMM + h * 64;
#pragma unroll
            for (int dj = 0; dj < 4; ++dj)
                aout[rg + dj * 16 + n16] = f2bf(o[ti][dj][r] * inv);
        }
    }
}

extern "C" void kernel_launch(void* const* d_in, const int* in_sizes, int n_in,
                              void* d_out, int out_size, void* d_ws, size_t ws_size,
                              hipStream_t stream) {
    const float* x    = (const float*)d_in[0];  // [4096][2048] fp32
    const float* Wqkv = (const float*)d_in[1];  // [3072][2048] fp32
    const float* Wout = (const float*)d_in[2];  // [2048][2048] fp32
    // d_in[3] = mask (fp32): causal applied analytically in-kernel
    float* out = (float*)d_out;                 // [4096][2048] fp32

    // Workspace, aliased by sequential lifetime (all offsets in u16 elems):
    //   qkv      [0, 24 MiB)   — live GEMM1 .. attn (V cols unwritten in modes 1/2)
    //   xb/aout  [24, 40 MiB)  — xb: cvt..GEMM1; aout: attn..GEMM2
    //   Wqkvb    [40, 52 MiB)  — cvt..GEMM1
    // mode 0 (ws < 56 MiB):  vtb aliases Wqkvb@40, Woutb@44 — both post-GEMM1
    // mode 1 (ws >= 56 MiB): vtb@52 (written by GEMM1 epilogue), Woutb@44 post-GEMM1
    // mode 2 (ws >= 64 MiB): vtb@52, Woutb@56 (cvt'd up front) — post_gemm1 ELIMINATED
    u16* qkv   = (u16*)d_ws;
    u16* xb    = qkv + (size_t)NQ * QKV_N;       // elem 12,582,912
    u16* aout  = xb;
    u16* R     = xb + (size_t)NQ * DIMM;         // elem 20,971,520 (40 MiB)
    const size_t MiB = 1024 * 1024;
    int mode = (ws_size >= 64 * MiB) ? 2 : (ws_size >= 56 * MiB) ? 1 : 0;
    u16* Wqkvb = R;                                           // 12 MiB
    u16* vtb   = (mode >= 1) ? R + 6291456 : R;               // fused: @52 MiB; else old
    u16* Woutb = (mode == 2) ? R + 6291456 + 2097152          // @56 MiB
                             : R + 2097152;                   // @44 MiB (post-GEMM1)
    u16* g1vt  = (mode >= 1) ? vtb : nullptr;                 // enables V-fusion epilogue

    dim3 blk(256);
    // mode 2: convert x + Wqkv + Wout up front (18432 blocks); else x + Wqkv (14336)
    cvt_all<<<(mode == 2 ? 18432 : 14336), blk, 0, stream>>>(x, xb, Wqkv, Wqkvb, Wout, Woutb);
    gemm_nt<false, true, 128, 128><<<dim3(QKV_N / 128, NQ / 128), blk, 0, stream>>>(xb, Wqkvb, qkv, NQ, QKV_N, DIMM, g1vt);
    if (mode == 0)      post_gemm1<<<4608, blk, 0, stream>>>(qkv, vtb, Wout, Woutb);
    else if (mode == 1) post_gemm1<<<4096, blk, 0, stream>>>(qkv, vtb, Wout, Woutb);
    // mode 2: no post_gemm1 — V written by GEMM1, Wout converted by cvt_all
    attn<<<dim3(1024), blk, 0, stream>>>(qkv, vtb, aout);
    // GEMM2: 64x128 tiles -> 1024 blocks = 4/CU (128² gave 512 = 2/CU -> 607 TF)
    gemm_nt<true, false, 64, 128><<<dim3(DIMM / 128, NQ / 64), blk, 0, stream>>>(aout, Woutb, out, NQ, DIMM, DIMM, nullptr);
}

// Round 15
// 260.406 us; speedup vs baseline: 1.0480x; 1.0433x over previous
//
#include <hip/hip_runtime.h>

#define DIMM 2048
#define SEQ 2048
#define NHEAD 32
#define NKV 8
#define QKV_N 3072   // (32 + 2*8) * 64
#define NQ 4096      // BATCH * SEQ
#define VCOL0 2560   // (NHEAD + NKV) * 64 — first V column; = 20 * 128 (tile-aligned)

typedef short bfrag __attribute__((ext_vector_type(8)));   // 8 bf16 = 4 VGPR (MFMA A/B)
typedef short h4 __attribute__((ext_vector_type(4)));      // 4 bf16 = 8B
typedef float ffrag __attribute__((ext_vector_type(4)));   // 4 f32 accumulator
typedef unsigned short u16;

__device__ inline u16 f2bf(float f) {
    union { float f; unsigned int u; } v; v.f = f;
    unsigned int r = (v.u + 0x7FFFu + ((v.u >> 16) & 1u)) >> 16;
    return (u16)r;
}
// pack two non-negative floats to bf16 pair (round-half-up; p>=0 here).
// v_perm_b32 form — BIT-IDENTICAL to the proven shift/and/or form (v5), 3 ops vs 5.
// (v_cvt_pk_bf16_f32 remains banned: round-0 failure, absmax 0.176.)
__device__ inline unsigned int pack2(float a, float b) {
    union { float f; unsigned int u; } x, y; x.f = a; y.f = b;
#if __has_builtin(__builtin_amdgcn_perm)
    return __builtin_amdgcn_perm(y.u + 0x8000u, x.u + 0x8000u, 0x07060302u);
#else
    return ((x.u + 0x8000u) >> 16) | ((y.u + 0x8000u) & 0xFFFF0000u);
#endif
}

// 2^x via the compiler intrinsic (single v_exp_f32 WITH correct hazard handling).
// LESSON (round 5): raw asm("v_exp_f32") NaN'd — VALU-TRANS-use hazard; the
// compiler's hazard recognizer can't see inside inline-asm. Never hand-roll TRANS.
__device__ inline float fexp2(float x) {
#if __has_builtin(__builtin_amdgcn_exp2f)
    return __builtin_amdgcn_exp2f(x);
#else
    return exp2f(x);
#endif
}

__device__ inline void cvt4(const float* __restrict__ src, u16* __restrict__ dst, int i) {
    float4 v = *(const float4*)(src + i);
    h4 o;
    o[0] = (short)f2bf(v.x); o[1] = (short)f2bf(v.y);
    o[2] = (short)f2bf(v.z); o[3] = (short)f2bf(v.w);
    *(h4*)(dst + i) = o;
}

// ---------------- fused fp32->bf16 convert: x + Wqkv ----------------
// Blocks [0,8192): x (8,388,608 f). [8192,14336): Wqkv (6,291,456 f).
// Wout conversion moved INTO attn (round 15): attn runs at 6% HBM (idle memory
// pipe) and Wout is only read by GEMM2 (launched after attn) — saves ~4 µs of
// serial BW-bound time here. Segment boundary block-aligned — no divergence.
__global__ void cvt_xw(const float* __restrict__ x, u16* __restrict__ xb,
                       const float* __restrict__ w, u16* __restrict__ wb) {
    int t = blockIdx.x * blockDim.x + threadIdx.x;
    if (t < 2097152) cvt4(x, xb, t * 4);
    else             cvt4(w, wb, (t - 2097152) * 4);
}

// async global->LDS, 16B per lane; LDS dest is wave-uniform base + lane*16 (HW rule)
__device__ inline void gl_lds16(const u16* g, u16* l) {
    __builtin_amdgcn_global_load_lds(
        (const __attribute__((address_space(1))) unsigned int*)g,
        (__attribute__((address_space(3))) unsigned int*)l, 16, 0, 0);
}

// Stage R x 64 bf16 tile (row stride gstride elems) into LDS via global_load_lds.
// XOR swizzle: LDS chunk p of row r holds global chunk p^(r&7). Conflict-free.
template<int R>
__device__ inline void stage64(const u16* __restrict__ g, int gstride, u16* lds) {
    int tid = threadIdx.x, w = tid >> 6, l = tid & 63;
#pragma unroll
    for (int i = 0; i < R / 32; ++i) {
        int row = w * (R / 4) + i * 8 + (l >> 3);
        int c = (l & 7) ^ (row & 7);
        gl_lds16(g + (size_t)row * gstride + c * 8, lds + (w * (R / 4) + i * 8) * 64);
    }
}

__device__ inline bfrag frag64(const u16* lds, int row, int ch) {
    return *(const bfrag*)(lds + row * 64 + (ch ^ (row & 7)) * 8);
}

// ---------------- NT GEMM (m97 single-buffer, tile-templated) ----------------
// C[M][N] = A[M][K] @ B[N][K]^T, bf16 in, fp32 accum. BMxBN tile, BK=64.
// GEMM1 (128x128): 768 blocks = 3/CU exact, ~908 TF — AT the m97-structure
// ceiling (m103: 912 at 4/CU; 3/CU ≈ 4/CU for this structure).
// GEMM2 (64x128): 1024 blocks = 4/CU (128² gave 512 = 2/CU -> 607 TF; round-14:
// out of top-5, <59 µs — kept). Same K-accumulation order -> bit-identical C.
// 256²/8-phase rejected (tile under-fill + unreconstructable schedule).
// NO setprio here (m190: null/negative on lockstep GEMM).
// SCALEQ: Q columns scaled by 1/sqrt(64)*log2(e) for attn's exp2.
// vt != nullptr (GEMM1, fusion modes): V columns (n0 >= VCOL0, block-uniform)
// written TRANSPOSED directly to vt (bit-identical to post_gemm1's transpose).
template<bool CF32, bool SCALEQ, int BM, int BN>
__global__ __launch_bounds__(256, (BM * BN == 16384) ? 3 : 4)
void gemm_nt(const u16* __restrict__ A, const u16* __restrict__ B,
             void* __restrict__ Cp, int M, int N, int K, u16* __restrict__ vt) {
    constexpr int TI = BM / 32;  // 16-row tiles per wave
    constexpr int TJ = BN / 32;  // 16-col tiles per wave
    __shared__ u16 As[BM * 64];
    __shared__ u16 Bs[BN * 64];
    int tid = threadIdx.x, lane = tid & 63, w = tid >> 6;
    int quad = lane >> 4, n16 = lane & 15;
    int wm = w >> 1, wn = w & 1;
    int m0 = blockIdx.y * BM, n0 = blockIdx.x * BN;

    ffrag acc[TI][TJ] = {};
    for (int k0 = 0; k0 < K; k0 += 64) {
        stage64<BM>(A + (size_t)m0 * K + k0, K, As);
        stage64<BN>(B + (size_t)n0 * K + k0, K, Bs);
        __syncthreads();
#pragma unroll
        for (int ks = 0; ks < 2; ++ks) {
            bfrag a[TI], b[TJ];
#pragma unroll
            for (int t = 0; t < TI; ++t) a[t] = frag64(As, wm * (BM / 2) + t * 16 + n16, ks * 4 + quad);
#pragma unroll
            for (int t = 0; t < TJ; ++t) b[t] = frag64(Bs, wn * (BN / 2) + t * 16 + n16, ks * 4 + quad);
#pragma unroll
            for (int ti = 0; ti < TI; ++ti)
#pragma unroll
                for (int tj = 0; tj < TJ; ++tj)
                    acc[ti][tj] = __builtin_amdgcn_mfma_f32_16x16x32_bf16(a[ti], b[tj], acc[ti][tj], 0, 0, 0);
        }
        __syncthreads();
    }
    // C/D layout: col = lane&15, row = quad*4 + r
    if constexpr (SCALEQ) {
        if (vt != nullptr && n0 >= VCOL0) {
            // V-fusion epilogue (block-uniform branch): write vt[(b*8+kh)*64+d][s]
#pragma unroll
            for (int ti = 0; ti < TI; ++ti) {
                int row0 = m0 + wm * (BM / 2) + ti * 16 + quad * 4;  // 4 consecutive rows = s0..s0+3
                int bb = row0 >> 11, s0 = row0 & (SEQ - 1);
#pragma unroll
                for (int tj = 0; tj < TJ; ++tj) {
                    int col = n0 + wn * (BN / 2) + tj * 16 + n16;
                    int kh = (col - VCOL0) >> 6, d = col & 63;
                    uint2 pk;
                    pk.x = (unsigned)f2bf(acc[ti][tj][0]) | ((unsigned)f2bf(acc[ti][tj][1]) << 16);
                    pk.y = (unsigned)f2bf(acc[ti][tj][2]) | ((unsigned)f2bf(acc[ti][tj][3]) << 16);
                    *(uint2*)(vt + (size_t)((bb * 8 + kh) * 64 + d) * SEQ + s0) = pk;
                }
            }
            return;
        }
    }
#pragma unroll
    for (int ti = 0; ti < TI; ++ti) {
        int row = m0 + wm * (BM / 2) + ti * 16 + quad * 4;
#pragma unroll
        for (int tj = 0; tj < TJ; ++tj) {
            int col = n0 + wn * (BN / 2) + tj * 16 + n16;
            // 0.125 * log2(e) = 0.18033688011112042
            float sc = (SCALEQ && col < NHEAD * 64) ? 0.18033688011112042f : 1.0f;
#pragma unroll
            for (int r = 0; r < 4; ++r) {
                if (CF32) ((float*)Cp)[(size_t)(row + r) * N + col] = acc[ti][tj][r];
                else      ((u16*)Cp)[(size_t)(row + r) * N + col] = f2bf(acc[ti][tj][r] * sc);
            }
        }
    }
}

// ---------------- post-GEMM1 pass (mode-0 fallback only) ----------------
__global__ void post_gemm1(const u16* __restrict__ qkv, u16* __restrict__ vt,
                           const float* __restrict__ Wout, u16* __restrict__ Woutb) {
    __shared__ u16 t[64][72];
    int bid = blockIdx.x, tid = threadIdx.x;
    if (bid < 4096) {
        cvt4(Wout, Woutb, (bid * 256 + tid) * 4);
        return;
    }
    int idx = bid - 4096;
    int s0 = (idx & 31) * 64, kh = (idx >> 5) & 7, b = idx >> 8;
    {
        int r = tid >> 2, c = tid & 3;
        const u16* gp = qkv + (size_t)(b * SEQ + s0 + r) * QKV_N + (NHEAD + NKV + kh) * 64 + c * 16;
        *(bfrag*)&t[r][c * 16] = *(const bfrag*)gp;
        *(bfrag*)&t[r][c * 16 + 8] = *(const bfrag*)(gp + 8);
    }
    __syncthreads();
    {
        int d = tid >> 2, c = tid & 3;
        u16* op = vt + (size_t)((b * 8 + kh) * 64 + d) * SEQ + s0 + c * 16;
        bfrag v0, v1;
#pragma unroll
        for (int j = 0; j < 8; ++j) ((u16*)&v0)[j] = t[c * 16 + j][d];
#pragma unroll
        for (int j = 0; j < 8; ++j) ((u16*)&v1)[j] = t[c * 16 + 8 + j][d];
        *(bfrag*)op = v0;
        *(bfrag*)(op + 8) = v1;
    }
}

// ---------------- Flash attention v14 + Wout-cvt rider (round 15) ----------------
// attn runs at ~6% HBM (latency-bound, idle memory pipe); Wout (16 MB read +
// 8 MB write) is only consumed by GEMM2, which launches after attn — so the
// conversion rides here: 16 floats/thread over 1024x256 threads, block-uniform,
// absorbed by attn's stalls (~+0.5-1 µs) vs ~4 µs serial in cvt. Also kills the
// last post_gemm1 launch in mode 1.
// Container-speed note (round 14): attn 55.2 vs 59.3 across rounds was clock
// drift (hbm_gbps 534->497, exact ratio) — compare rates, not just dur.
// v16's GQA K/V-sharing REJECTED (L2 already absorbed duplicates; coarser
// barriers cost MfmaUtil). v12's bpermute REJECTED. setprio kept (m191 regime).
// v9 invariants (PROTECT): linear heavy-first dispatch qb = 15-(id>>6) — fixes
// drain tail AND gives L2 K/V sharing (FETCH 43->12 MB); ones-column MFMA
// denominator in C-layout; exp2 with log2e folded into Q scale at GEMM1;
// Ps XOR-swizzled [128][64] (conflict-free frag64 reads).
// LDS: 16K (K) + 16K (V) + 16K (Ps) = 48 KB -> 3 blocks/CU.

template<bool MASKED>
__device__ inline void st_phase(int kb, int rowbase, int quad, int n16, int wrow,
                                const bfrag qf[2][2], const u16* Ks, u16* Ps) {
#pragma unroll
    for (int tj = 0; tj < 4; ++tj) {
        bfrag kf0 = frag64(Ks, tj * 16 + n16, quad);
        bfrag kf1 = frag64(Ks, tj * 16 + n16, 4 + quad);
        ffrag st[2] = {};
        __builtin_amdgcn_s_setprio(1);
#pragma unroll
        for (int ti = 0; ti < 2; ++ti) {
            st[ti] = __builtin_amdgcn_mfma_f32_16x16x32_bf16(kf0, qf[ti][0], st[ti], 0, 0, 0);
            st[ti] = __builtin_amdgcn_mfma_f32_16x16x32_bf16(kf1, qf[ti][1], st[ti], 0, 0, 0);
        }
        __builtin_amdgcn_s_setprio(0);
        int key0 = kb * 64 + tj * 16 + quad * 4;  // this lane's 4 consecutive keys
#pragma unroll
        for (int ti = 0; ti < 2; ++ti) {
            int qrow = rowbase + ti * 16 + n16;   // global q row (col of S^T tile)
            float p[4];
#pragma unroll
            for (int r = 0; r < 4; ++r) {
                float e = fexp2(st[ti][r]);
                if (MASKED && (key0 + r > qrow)) e = 0.f;
                p[r] = e;
            }
            uint2 pk; pk.x = pack2(p[0], p[1]); pk.y = pack2(p[2], p[3]);
            // swizzled write: logical col tj*16+quad*4 -> chunk tj*2+(quad>>1),
            // chunk stored at ^(row&7), half-offset (quad&1)*4. 8B-aligned.
            int prow = wrow + ti * 16 + n16;
            int c0 = (tj * 2 + (quad >> 1)) ^ (prow & 7);
            *(uint2*)(Ps + prow * 64 + c0 * 8 + (quad & 1) * 4) = pk;
        }
    }
}

__device__ inline void pv_phase(const bfrag pf[4], const u16* Vs, ffrag o[2][4],
                                ffrag ol[2], bfrag ones, int quad, int n16) {
#pragma unroll
    for (int ks = 0; ks < 2; ++ks) {
        bfrag vf[4];
#pragma unroll
        for (int dj = 0; dj < 4; ++dj) vf[dj] = frag64(Vs, dj * 16 + n16, ks * 4 + quad);
        __builtin_amdgcn_s_setprio(1);
#pragma unroll
        for (int ti = 0; ti < 2; ++ti) {
#pragma unroll
            for (int dj = 0; dj < 4; ++dj)
                o[ti][dj] = __builtin_amdgcn_mfma_f32_16x16x32_bf16(pf[ks * 2 + ti], vf[dj], o[ti][dj], 0, 0, 0);
            // denominator: l = P @ 1 — already in C-layout (row = quad*4 + r)
            ol[ti] = __builtin_amdgcn_mfma_f32_16x16x32_bf16(pf[ks * 2 + ti], ones, ol[ti], 0, 0, 0);
        }
        __builtin_amdgcn_s_setprio(0);
    }
}

__global__ __launch_bounds__(256, 3) void attn(const u16* __restrict__ qkv,
                                               const u16* __restrict__ vt,
                                               u16* __restrict__ aout,
                                               const float* __restrict__ wo,
                                               u16* __restrict__ wob) {
    __shared__ u16 Ks[2][64 * 64];
    __shared__ u16 Vs[2][64 * 64];
    __shared__ u16 Ps[128 * 64];

    int tid = threadIdx.x, lane = tid & 63, w = tid >> 6;
    int quad = lane >> 4, n16 = lane & 15;
    // linear heavy-first mapping: blocks 0..63 are qb=15 (heaviest), last 64 are qb=0
    int id = blockIdx.x;

    // Wout fp32->bf16 rider (modes 1/2): 16 floats/thread, rides attn's idle BW.
    // wob only read by GEMM2 (launched after attn) — stream order guarantees safety.
    if (wo != nullptr) {
        int t = id * 256 + tid;
#pragma unroll
        for (int j = 0; j < 4; ++j) cvt4(wo, wob, t * 16 + j * 4);
    }

    int qb = 15 - (id >> 6);
    int h = id & 31, b = (id >> 5) & 1;
    int kh = h & 7;  // jnp.tile semantics: kv head = h % NKV
    int wrow = w * 32;  // wave's local row base in Ps

    bfrag ones;
#pragma unroll
    for (int j = 0; j < 8; ++j) ((u16*)&ones)[j] = (short)0x3F80;  // bf16 1.0

    const u16* Qg = qkv + (size_t)(b * SEQ) * QKV_N + h * 64;  // pre-scaled by log2e/8
    const u16* Kg = qkv + (size_t)(b * SEQ) * QKV_N + (NHEAD + kh) * 64;
    const u16* Vg = vt + (size_t)((b * 8 + kh) * 64) * SEQ;

    int q0 = qb * 128;
    int rowbase = q0 + wrow;

    // Q fragments straight from global (B-operand layout: n16 = q-row, quad = d-chunk)
    bfrag qf[2][2];
#pragma unroll
    for (int ti = 0; ti < 2; ++ti)
#pragma unroll
        for (int ks = 0; ks < 2; ++ks)
            qf[ti][ks] = *(const bfrag*)(Qg + (size_t)(rowbase + ti * 16 + n16) * QKV_N + ks * 32 + quad * 8);

    ffrag o[2][4] = {};
    ffrag ol[2] = {};
    bfrag pf[4];

    int nkb = 2 * qb + 2;  // 64-key blocks covering keys <= q0+127
    stage64<64>(Kg, QKV_N, Ks[0]);
    __syncthreads();
    for (int i = 0; i <= nkb; ++i) {
        // prefetch: K one block ahead, V for the current S^T block (lag-1 consumer)
        if (i + 1 < nkb) stage64<64>(Kg + (size_t)((i + 1) * 64) * QKV_N, QKV_N, Ks[(i + 1) & 1]);
        if (i < nkb)     stage64<64>(Vg + i * 64, SEQ, Vs[i & 1]);
        if (i > 0) {
            // read P(i-1) into regs — written last iteration, no lgkm stall.
            // frag64 = swizzle-matched read, conflict-free (GEMM-proven pattern).
#pragma unroll
            for (int ks = 0; ks < 2; ++ks)
#pragma unroll
                for (int ti = 0; ti < 2; ++ti)
                    pf[ks * 2 + ti] = frag64(Ps, wrow + ti * 16 + n16, ks * 4 + quad);
        }
        if (i < nkb) {
            if (i >= nkb - 2) st_phase<true>(i, rowbase, quad, n16, wrow, qf, Ks[i & 1], Ps);
            else              st_phase<false>(i, rowbase, quad, n16, wrow, qf, Ks[i & 1], Ps);
        }
        if (i > 0) pv_phase(pf, Vs[(i - 1) & 1], o, ol, ones, quad, n16);
        __syncthreads();  // drains prefetch (after compute) + guards buffer reuse
    }

    // ol[ti][r] holds the row-sum for qrow = rowbase + ti*16 + quad*4 + r
    // (identical across n16) — already in C-layout, no cross-lane reduce needed.
#pragma unroll
    for (int ti = 0; ti < 2; ++ti) {
#pragma unroll
        for (int r = 0; r < 4; ++r) {
            float inv = 1.f / ol[ti][r];
            size_t rg = (size_t)(b * SEQ + rowbase + ti * 16 + quad * 4 + r) * DIMM + h * 64;
#pragma unroll
            for (int dj = 0; dj < 4; ++dj)
                aout[rg + dj * 16 + n16] = f2bf(o[ti][dj][r] * inv);
        }
    }
}

extern "C" void kernel_launch(void* const* d_in, const int* in_sizes, int n_in,
                              void* d_out, int out_size, void* d_ws, size_t ws_size,
                              hipStream_t stream) {
    const float* x    = (const float*)d_in[0];  // [4096][2048] fp32
    const float* Wqkv = (const float*)d_in[1];  // [3072][2048] fp32
    const float* Wout = (const float*)d_in[2];  // [2048][2048] fp32
    // d_in[3] = mask (fp32): causal applied analytically in-kernel
    float* out = (float*)d_out;                 // [4096][2048] fp32

    // Workspace, aliased by sequential lifetime (all offsets in u16 elems):
    //   qkv      [0, 24 MiB)   — live GEMM1 .. attn (V cols unwritten in modes 1/2)
    //   xb/aout  [24, 40 MiB)  — xb: cvt..GEMM1; aout: attn..GEMM2
    //   Wqkvb    [40, 52 MiB)  — cvt..GEMM1
    // mode 0 (ws < 56 MiB):  vtb aliases Wqkvb@40, Woutb@44 — both post-GEMM1
    // mode 1 (ws >= 56 MiB): vtb@52 (GEMM1 epilogue), Woutb@44 (attn rider;
    //                        overlaps Wqkvb but attn runs after GEMM1) — 4 dispatches
    // mode 2 (ws >= 64 MiB): vtb@52, Woutb@56 (attn rider) — 4 dispatches
    u16* qkv   = (u16*)d_ws;
    u16* xb    = qkv + (size_t)NQ * QKV_N;       // elem 12,582,912
    u16* aout  = xb;
    u16* R     = xb + (size_t)NQ * DIMM;         // elem 20,971,520 (40 MiB)
    const size_t MiB = 1024 * 1024;
    int mode = (ws_size >= 64 * MiB) ? 2 : (ws_size >= 56 * MiB) ? 1 : 0;
    u16* Wqkvb = R;                                           // 12 MiB
    u16* vtb   = (mode >= 1) ? R + 6291456 : R;               // fused: @52 MiB; else old
    u16* Woutb = (mode == 2) ? R + 6291456 + 2097152          // @56 MiB
                             : R + 2097152;                   // @44 MiB
    u16* g1vt  = (mode >= 1) ? vtb : nullptr;                 // enables V-fusion epilogue
    const float* attn_wo = (mode >= 1) ? Wout : nullptr;      // attn Wout-cvt rider

    dim3 blk(256);
    cvt_xw<<<14336, blk, 0, stream>>>(x, xb, Wqkv, Wqkvb);
    gemm_nt<false, true, 128, 128><<<dim3(QKV_N / 128, NQ / 128), blk, 0, stream>>>(xb, Wqkvb, qkv, NQ, QKV_N, DIMM, g1vt);
    if (mode == 0) post_gemm1<<<4608, blk, 0, stream>>>(qkv, vtb, Wout, Woutb);
    // modes 1/2: V written by GEMM1 epilogue, Wout converted inside attn
    attn<<<dim3(1024), blk, 0, stream>>>(qkv, vtb, aout, attn_wo, Woutb);
    // GEMM2: 64x128 tiles -> 1024 blocks = 4/CU (128² gave 512 = 2/CU -> 607 TF)
    gemm_nt<true, false, 64, 128><<<dim3(DIMM / 128, NQ / 64), blk, 0, stream>>>(aout, Woutb, out, NQ, DIMM, DIMM, nullptr);
}